// Round 18
// baseline (202.356 us; speedup 1.0000x reference)
//
#include <hip/hip_runtime.h>
#include <math.h>

// CrossAttention B=2,S=2048,E=1024,H=16,Dh=64,NC=768 — fp32 in/out.
// Ledger: R11 216.4 | R19 208.2 | R21 203.5 | R22 196.8 BEST (reruns 199.3,
//   200.0 -> band 197-200) | R23/R25 tile-shrink REFUTED both gemms/attn.
// R27: attn de-staged (Common-mistake #7 / m169: K/V is L2-resident —
//   FETCH 12.3MB << 24MB unique — so LDS staging + per-iter barrier is
//   pure overhead). New attn: NO LDS, NO barriers; each wave loads its
//   K/V fragments directly from global (frag-order => per-lane address
//   khead + it*4096 + kc*512 + lane*8, coalesced 1KB/instr, L2-hit).
//   All 5 prior attn variants kept the barrier; this decouples waves
//   entirely. L2 traffic ~1.0GB => >=30us at 34.5TB/s ceiling; target
//   36-42us vs 48.6. Everything else byte-identical to R26.

namespace {

typedef short bfr __attribute__((ext_vector_type(8)));   // 8 bf16 = 4 VGPR
typedef short s4v __attribute__((ext_vector_type(4)));
typedef unsigned u4v __attribute__((ext_vector_type(4)));
typedef float accf __attribute__((ext_vector_type(16)));

#define MFMA32(a, b, c) __builtin_amdgcn_mfma_f32_32x32x16_bf16(a, b, c, 0, 0, 0)

__device__ inline short f2bf(float f) {  // RNE
    unsigned u = __float_as_uint(f);
    u += 0x7fffu + ((u >> 16) & 1u);
    return (short)(u >> 16);
}
__device__ inline float bf2f(short s) {
    return __uint_as_float(((unsigned)(unsigned short)s) << 16);
}
__device__ inline float fexp2(float x) { return __builtin_amdgcn_exp2f(x); }
__device__ inline accf zero16() {
    accf z;
#pragma unroll
    for (int i = 0; i < 16; ++i) z[i] = 0.f;
    return z;
}
__device__ inline void dma16(const void* g, void* l) {
    __builtin_amdgcn_global_load_lds(
        (const __attribute__((address_space(1))) void*)g,
        (__attribute__((address_space(3))) void*)l, 16, 0, 0);
}

// ---------- prep: tobf (x,ctx) + all 4 weight transposes, one dispatch ----
__global__ __launch_bounds__(256) void prep(
    const float* __restrict__ x, const float* __restrict__ ctx,
    short* __restrict__ xb, short* __restrict__ cb,
    const float* __restrict__ Wq, const float* __restrict__ Wk,
    const float* __restrict__ Wv, const float* __restrict__ Wo,
    short* __restrict__ Wqt, short* __restrict__ Wkt,
    short* __restrict__ Wvt, short* __restrict__ Wot) {
    __shared__ short t[64][68];
    const int bx = blockIdx.x;
    if (bx < 7168) {  // elementwise fp32->bf16
        int i = bx * 256 + threadIdx.x;
        if (i < 1048576) {
            float4 v = ((const float4*)x)[i];
            s4v p = {f2bf(v.x), f2bf(v.y), f2bf(v.z), f2bf(v.w)};
            ((s4v*)xb)[i] = p;
        } else {
            int j = i - 1048576;
            float4 v = ((const float4*)ctx)[j];
            s4v p = {f2bf(v.x), f2bf(v.y), f2bf(v.z), f2bf(v.w)};
            ((s4v*)cb)[j] = p;
        }
        return;
    }
    const int idx = bx - 7168;  // 0..1023
    const int z = idx >> 8, gy = (idx >> 4) & 15, gx = idx & 15;
    const float* W;
    short* Wt;
    int K;
    switch (z) {
        case 0: W = Wq; Wt = Wqt; K = 1024; break;
        case 1: W = Wk; Wt = Wkt; K = 768; break;
        case 2: W = Wv; Wt = Wvt; K = 768; break;
        default: W = Wo; Wt = Wot; K = 1024; break;
    }
    const int k0 = gy * 64;
    if (k0 >= K) return;
    const int tid = threadIdx.x;
    const int n0 = gx * 64;
    const int kr = tid >> 4, nc = (tid & 15) * 4;
#pragma unroll
    for (int rep = 0; rep < 4; ++rep) {
        int k = kr + rep * 16;
        float4 v = *(const float4*)&W[(size_t)(k0 + k) * 1024 + n0 + nc];
        t[nc + 0][k] = f2bf(v.x);
        t[nc + 1][k] = f2bf(v.y);
        t[nc + 2][k] = f2bf(v.z);
        t[nc + 3][k] = f2bf(v.w);
    }
    __syncthreads();
    const int nr = tid >> 4, kc = (tid & 15) * 4;
#pragma unroll
    for (int rep = 0; rep < 4; ++rep) {
        int n = nr + rep * 16;
        s4v p = {t[n][kc], t[n][kc + 1], t[n][kc + 2], t[n][kc + 3]};
        *(s4v*)&Wt[(size_t)(n0 + n) * K + k0 + kc] = p;
    }
}

// ---------- fused Q/K/V projection GEMM, 512 thr / 8 waves ----------------
// R19: 3-deep counted-vmcnt pipeline. XCD-swizzled 1D grid (768):
// z = bid>>8; local = bid&255; m = local&31, n = local>>5.
__global__ __launch_bounds__(512, 6) void gemm_qkv(
    const short* __restrict__ xb, const short* __restrict__ cb,
    const short* __restrict__ Wqt, const short* __restrict__ Wkt,
    const short* __restrict__ Wvt, const float* __restrict__ bq,
    const float* __restrict__ bk, const float* __restrict__ bv,
    short* __restrict__ Qf, short* __restrict__ Kf, short* __restrict__ Vt,
    float qscale) {
    const int bid = blockIdx.x;
    const int z = bid >> 8;
    const int local = bid & 255;
    const short* A  = (z == 0) ? xb : cb;
    const short* Bt = (z == 0) ? Wqt : ((z == 1) ? Wkt : Wvt);
    const float* bias = (z == 0) ? bq : ((z == 1) ? bk : bv);
    const int K = (z == 0) ? 1024 : 768;
    const int NIT = K / 32;
    const float scale = (z == 0) ? qscale : 1.f;
    short* out = (z == 0) ? Qf : ((z == 1) ? Kf : Vt);

    __shared__ short As[12288];  // 3 x 4096 (triple buffer)
    __shared__ short Bs[12288];
    const int t = threadIdx.x, lane = t & 63, w = t >> 6;  // w 0..7
    const int lm = lane & 31, h2 = lane >> 5;
    const int wm = w & 1, wn = w >> 1;  // wn 0..3
    const int m0 = (local & 31) * 128, n0 = (local >> 5) * 128;

    const int st = t ^ ((t >> 3) & 7);
    const int srow = st >> 2, scol = (st & 3) * 8;
    const short* ga = A + (size_t)(m0 + srow) * K + scol;
    const short* gb = Bt + (size_t)(n0 + srow) * K + scol;

    const int xorv = (lm >> 1) & 7;
    const int rA0 = wm * 64 + lm, rB0 = wn * 32 + lm;

    accf acc[2] = {zero16(), zero16()};

    dma16(ga, &As[w * 512]);
    dma16(gb, &Bs[w * 512]);
    __builtin_amdgcn_sched_barrier(0);
    dma16(ga + 32, &As[4096 + w * 512]);
    dma16(gb + 32, &Bs[4096 + w * 512]);
    __builtin_amdgcn_sched_barrier(0);

    int buf = 0;
#pragma unroll 1
    for (int it = 0; it < NIT; ++it) {
        __builtin_amdgcn_sched_barrier(0);
        asm volatile("s_waitcnt vmcnt(2)" ::: "memory");
        __builtin_amdgcn_s_barrier();
        __builtin_amdgcn_sched_barrier(0);
        {
            const int nx = (it + 2 >= NIT) ? (it + 2 - NIT) : (it + 2);
            const int nb = (buf + 2 >= 3) ? (buf - 1) : (buf + 2);
            dma16(ga + nx * 32, &As[nb * 4096 + w * 512]);
            dma16(gb + nx * 32, &Bs[nb * 4096 + w * 512]);
        }
        const short* bA = &As[buf * 4096];
        const short* bB = &Bs[buf * 4096];
#pragma unroll
        for (int kk8 = 0; kk8 < 4; kk8 += 2) {
            bfr a0 = *(const bfr*)&bA[((rA0 * 4 + h2 + kk8) ^ xorv) * 8];
            bfr a1 = *(const bfr*)&bA[(((rA0 + 32) * 4 + h2 + kk8) ^ xorv) * 8];
            bfr b0 = *(const bfr*)&bB[((rB0 * 4 + h2 + kk8) ^ xorv) * 8];
            acc[0] = MFMA32(a0, b0, acc[0]);
            acc[1] = MFMA32(a1, b0, acc[1]);
        }
        buf = (buf + 1 == 3) ? 0 : buf + 1;
    }
    asm volatile("s_waitcnt vmcnt(0)" ::: "memory");
    __builtin_amdgcn_sched_barrier(0);

    const int n = n0 + wn * 32 + lm;
    const float bn = bias[n];
    const int hh = n >> 6, dd = n & 63;
#pragma unroll
    for (int mt = 0; mt < 2; ++mt) {
        const int mbase = m0 + wm * 64 + mt * 32 + 4 * h2;
        if (z != 2) {
            const int cb2 = (dd >> 4) * 512 + ((dd >> 3) & 1) * 256 + (dd & 7);
#pragma unroll
            for (int r = 0; r < 16; ++r) {
                const int m = mbase + (r & 3) + 8 * (r >> 2);
                const int bb = m >> 11, q = m & 2047;
                float v = (acc[mt][r] + bn) * scale;
                out[((size_t)((bb * 16 + hh) * 64 + (q >> 5))) * 2048 +
                    cb2 + (q & 31) * 8] = f2bf(v);
            }
        } else {
            const int dblk = dd >> 5, lmv = dd & 31;
#pragma unroll
            for (int g = 0; g < 4; ++g) {
                const int m = mbase + 8 * g;
                const int bb = m >> 11, s = m & 2047;
                const int kvt = s >> 6, kc = (s >> 4) & 3;
                const int h2v = (s >> 3) & 1, j0 = s & 7;
                s4v pq = {f2bf(acc[mt][4 * g + 0] + bn),
                          f2bf(acc[mt][4 * g + 1] + bn),
                          f2bf(acc[mt][4 * g + 2] + bn),
                          f2bf(acc[mt][4 * g + 3] + bn)};
                *(s4v*)(out +
                        ((size_t)(((bb * 16 + hh) * 32 + kvt) * 2 + dblk)) * 2048 +
                        kc * 512 + h2v * 256 + lmv * 8 + j0) = pq;
            }
        }
    }
}

// ---------- output GEMM: 128x64 tiles, 3-deep counted-vmcnt (R22) ---------
__global__ __launch_bounds__(512, 6) void gemm_o(
    const short* __restrict__ Af, const short* __restrict__ Bt,
    const float* __restrict__ bias, float* __restrict__ out) {
    constexpr int K = 1024, NIT = 32;
    __shared__ short As[12288];  // 3 x 4096
    __shared__ short Bs[6144];   // 3 x 2048
    const int t = threadIdx.x, lane = t & 63, w = t >> 6;  // w 0..7
    const int lm = lane & 31, h2 = lane >> 5;
    const int wm = w & 3, wn = w >> 2;  // wm 0..3, wn 0..1
    const int bid = blockIdx.x;
    const int m0 = (bid & 31) * 128, n0 = (bid >> 5) * 64;

    const int st = t ^ ((t >> 3) & 7);
    const int srow = st >> 2, scol = (st & 3) * 8;
    const short* ga = Af + (size_t)(m0 + srow) * K + scol;
    const short* gb = Bt + (size_t)(n0 + srow) * K + scol;  // used t<256
    const bool bw = (w < 4);  // wave-uniform: B-staging waves

    const int xorv = (lm >> 1) & 7;
    const int rA0 = wm * 32 + lm, rB0 = wn * 32 + lm;

    accf acc = zero16();

    // prologue: batches 0,1
    dma16(ga, &As[w * 512]);
    if (bw) dma16(gb, &Bs[w * 512]);
    __builtin_amdgcn_sched_barrier(0);
    dma16(ga + 32, &As[4096 + w * 512]);
    if (bw) dma16(gb + 32, &Bs[2048 + w * 512]);
    __builtin_amdgcn_sched_barrier(0);

    int buf = 0;
#pragma unroll 1
    for (int it = 0; it < NIT; ++it) {
        __builtin_amdgcn_sched_barrier(0);
        if (bw) {
            asm volatile("s_waitcnt vmcnt(2)" ::: "memory");
        } else {
            asm volatile("s_waitcnt vmcnt(1)" ::: "memory");
        }
        __builtin_amdgcn_s_barrier();
        __builtin_amdgcn_sched_barrier(0);
        {
            const int nx = (it + 2 >= NIT) ? (it + 2 - NIT) : (it + 2);
            const int nb = (buf + 2 >= 3) ? (buf - 1) : (buf + 2);
            dma16(ga + nx * 32, &As[nb * 4096 + w * 512]);
            if (bw) dma16(gb + nx * 32, &Bs[nb * 2048 + w * 512]);
        }
        const short* bA = &As[buf * 4096];
        const short* bB = &Bs[buf * 2048];
#pragma unroll
        for (int kk8 = 0; kk8 < 4; kk8 += 2) {
            bfr a0 = *(const bfr*)&bA[((rA0 * 4 + h2 + kk8) ^ xorv) * 8];
            bfr b0 = *(const bfr*)&bB[((rB0 * 4 + h2 + kk8) ^ xorv) * 8];
            acc = MFMA32(a0, b0, acc);
        }
        buf = (buf + 1 == 3) ? 0 : buf + 1;
    }
    asm volatile("s_waitcnt vmcnt(0)" ::: "memory");
    __builtin_amdgcn_sched_barrier(0);

    const int n = n0 + wn * 32 + lm;
    const float bn = bias[n];
    const int mbase = m0 + wm * 32 + 4 * h2;
#pragma unroll
    for (int r = 0; r < 16; ++r) {
        const int m = mbase + (r & 3) + 8 * (r >> 2);
        out[(size_t)m * 1024 + n] = acc[r] + bn;
    }
}

// ---------- flash attention: NO LDS, NO barriers — direct L2 reads (R27) --
// Grid 512: hidx = bid&31, qb = bid>>5. 4 fully independent waves/block.
// Fragments read straight from frag-order Kf/Vt: K(it) at khead+it*4096,
// V(it) at vhead+it*4096 (+2048 for second half) — addresses identical to
// the old LDS reads, coalesced 1KB/instruction, L2-resident working set.
__global__ __launch_bounds__(256) void attn(
    const short* __restrict__ Qf, const short* __restrict__ Kf,
    const short* __restrict__ Vt, short* __restrict__ part) {
    const int bid = blockIdx.x;
    const int hidx = bid & 31, qb = bid >> 5;
    const int b = hidx >> 4, h = hidx & 15;
    const int lane = threadIdx.x & 63, wv = threadIdx.x >> 6;
    const int lm = lane & 31, h2 = lane >> 5;
    const bool hb = h2 != 0;
    const int q0 = qb * 128 + wv * 32;

    const short* qbase =
        Qf + ((size_t)(hidx * 64 + (q0 >> 5))) * 2048 + lane * 8;
    bfr qf[4];
#pragma unroll
    for (int kc = 0; kc < 4; ++kc) qf[kc] = *(const bfr*)(qbase + kc * 512);

    const short* khead = Kf + (size_t)hidx * 131072 + lane * 8;
    const short* vhead = Vt + (size_t)hidx * 131072 + lane * 8;

    accf oa0 = zero16(), oa1 = zero16();
    float la0 = 0.f, la1 = 0.f;

#pragma unroll 1
    for (int it = 0; it < 32; ++it) {
        const short* kit = khead + (size_t)it * 4096;
        const short* vit = vhead + (size_t)it * 4096;
        bfr kf0[4], kf1[4], vf0[4], vf1[4];
#pragma unroll
        for (int kc = 0; kc < 4; ++kc) {
            kf0[kc] = *(const bfr*)(kit + kc * 512);
            kf1[kc] = *(const bfr*)(kit + 2048 + kc * 512);
            vf0[kc] = *(const bfr*)(vit + kc * 512);
            vf1[kc] = *(const bfr*)(vit + 2048 + kc * 512);
        }
        accf s0 = zero16(), s1 = zero16();
#pragma unroll
        for (int kc = 0; kc < 4; ++kc) {
            s0 = MFMA32(kf0[kc], qf[kc], s0);
            s1 = MFMA32(kf1[kc], qf[kc], s1);
        }

#pragma unroll
        for (int i = 0; i < 16; ++i) s0[i] = fexp2(s0[i]);
#pragma unroll
        for (int i = 0; i < 16; ++i) s1[i] = fexp2(s1[i]);
#pragma unroll
        for (int i = 0; i < 16; ++i) {
            if (i & 1) la1 += s0[i] + s1[i];
            else       la0 += s0[i] + s1[i];
        }

        // packed half-swap transpose
        bfr pb[4];
#pragma unroll
        for (int kc = 0; kc < 4; ++kc) {
            const accf& s = (kc < 2) ? s0 : s1;
            const int base = 8 * (kc & 1);
            unsigned Lw0 = __builtin_amdgcn_perm(__float_as_uint(s[base + 1]),
                                                 __float_as_uint(s[base + 0]),
                                                 0x07060302u);
            unsigned Lw1 = __builtin_amdgcn_perm(__float_as_uint(s[base + 3]),
                                                 __float_as_uint(s[base + 2]),
                                                 0x07060302u);
            unsigned Hw0 = __builtin_amdgcn_perm(__float_as_uint(s[base + 5]),
                                                 __float_as_uint(s[base + 4]),
                                                 0x07060302u);
            unsigned Hw1 = __builtin_amdgcn_perm(__float_as_uint(s[base + 7]),
                                                 __float_as_uint(s[base + 6]),
                                                 0x07060302u);
            unsigned c0 = hb ? Lw0 : Hw0;
            unsigned c1 = hb ? Lw1 : Hw1;
            unsigned r0 = (unsigned)__shfl_xor((int)c0, 32);
            unsigned r1 = (unsigned)__shfl_xor((int)c1, 32);
            u4v pw = {hb ? r0 : Lw0, hb ? r1 : Lw1,
                      hb ? Hw0 : r0, hb ? Hw1 : r1};
            pb[kc] = __builtin_bit_cast(bfr, pw);
        }

#pragma unroll
        for (int kc = 0; kc < 4; ++kc) {
            oa0 = MFMA32(vf0[kc], pb[kc], oa0);
            oa1 = MFMA32(vf1[kc], pb[kc], oa1);
        }
    }

    float ls = la0 + la1;
    ls += __shfl_xor(ls, 32);
    const float iv = 1.f / ls;

    short* orow = part + (size_t)(b * 2048 + q0 + lm) * 1024 + h * 64;
#pragma unroll
    for (int dt = 0; dt < 2; ++dt) {
        const accf& oa = dt ? oa1 : oa0;
#pragma unroll
        for (int g = 0; g < 4; ++g) {
            const int d0 = dt * 32 + 4 * h2 + 8 * g;
            s4v p = {f2bf(oa[4 * g + 0] * iv), f2bf(oa[4 * g + 1] * iv),
                     f2bf(oa[4 * g + 2] * iv), f2bf(oa[4 * g + 3] * iv)};
            *(s4v*)(orow + d0) = p;
        }
    }
}

}  // namespace

extern "C" void kernel_launch(void* const* d_in, const int* in_sizes, int n_in,
                              void* d_out, int out_size, void* d_ws,
                              size_t ws_size, hipStream_t stream) {
    const float* x   = (const float*)d_in[0];
    const float* ctx = (const float*)d_in[1];
    const float* Wq  = (const float*)d_in[2];
    const float* bq  = (const float*)d_in[3];
    const float* Wk  = (const float*)d_in[4];
    const float* bk  = (const float*)d_in[5];
    const float* Wv  = (const float*)d_in[6];
    const float* bv  = (const float*)d_in[7];
    const float* Wo  = (const float*)d_in[8];
    const float* bo  = (const float*)d_in[9];

    short* xb  = (short*)d_ws;
    short* cb  = xb + (size_t)4096 * 1024;
    short* Wqt = cb + (size_t)4096 * 768;
    short* Wkt = Wqt + (size_t)1024 * 1024;
    short* Wvt = Wkt + (size_t)1024 * 768;
    short* Wot = Wvt + (size_t)1024 * 768;
    short* Qf  = Wot + (size_t)1024 * 1024;  // frag-order, pre-scaled
    short* Kf  = Qf + (size_t)4096 * 1024;   // frag-order
    short* Vt  = Kf + (size_t)4096 * 1024;   // frag-order V^T
    short* p0  = Vt + (size_t)4096 * 1024;   // final normalized attn out

    prep<<<8192, 256, 0, stream>>>(x, ctx, xb, cb, Wq, Wk, Wv, Wo,
                                   Wqt, Wkt, Wvt, Wot);

    const float qscale = 0.125f * 1.44269504088896f;
    gemm_qkv<<<768, 512, 0, stream>>>(xb, cb, Wqt, Wkt, Wvt,
                                      bq, bk, bv, Qf, Kf, Vt, qscale);

    attn<<<512, 256, 0, stream>>>(Qf, Kf, Vt, p0);

    gemm_o<<<512, 512, 0, stream>>>(p0, Wot, bo, (float*)d_out);
}

// Round 19
// 199.274 us; speedup vs baseline: 1.0155x; 1.0155x over previous
//
#include <hip/hip_runtime.h>
#include <math.h>

// CrossAttention B=2,S=2048,E=1024,H=16,Dh=64,NC=768 — fp32 in/out.
// FINAL = R22 config (session best 196.8us; reruns 199.3/200.0).
// Session ledger (baseline 216.7):
//   R18 qkv 4w->8w: -6us | R19 qkv 3-deep counted-vmcnt + attn merge:
//   -7us | R21 combine hoisted out of gemm_out: -5us | R22 attn full-KV
//   in-reg normalize + gemm_o 128x64: -7us => 196.8 BEST.
// Refuted (all reverted): R13/R16/R17-split/R23/R27 attn variants
//   (counted-vmcnt, split4, 2-dispatch, 2-wave-reuse, de-staged L2-direct
//   — attn is latency-bound on the per-wave chain at >=8 waves/CU; the
//   simple dbuf+barrier structure wins); R20/R25 tile-shrink on both
//   gemms (compute-per-barrier halves faster than latency hiding gains).
// Remaining timed window: ~81us fixed harness fills + attn 48.6 + qkv ~36
//   + gemm_o ~16 + prep ~15.

namespace {

typedef short bfr __attribute__((ext_vector_type(8)));   // 8 bf16 = 4 VGPR
typedef short s4v __attribute__((ext_vector_type(4)));
typedef unsigned u4v __attribute__((ext_vector_type(4)));
typedef float accf __attribute__((ext_vector_type(16)));

#define MFMA32(a, b, c) __builtin_amdgcn_mfma_f32_32x32x16_bf16(a, b, c, 0, 0, 0)

__device__ inline short f2bf(float f) {  // RNE
    unsigned u = __float_as_uint(f);
    u += 0x7fffu + ((u >> 16) & 1u);
    return (short)(u >> 16);
}
__device__ inline float bf2f(short s) {
    return __uint_as_float(((unsigned)(unsigned short)s) << 16);
}
__device__ inline float fexp2(float x) { return __builtin_amdgcn_exp2f(x); }
__device__ inline accf zero16() {
    accf z;
#pragma unroll
    for (int i = 0; i < 16; ++i) z[i] = 0.f;
    return z;
}
__device__ inline void dma16(const void* g, void* l) {
    __builtin_amdgcn_global_load_lds(
        (const __attribute__((address_space(1))) void*)g,
        (__attribute__((address_space(3))) void*)l, 16, 0, 0);
}

// ---------- prep: tobf (x,ctx) + all 4 weight transposes, one dispatch ----
__global__ __launch_bounds__(256) void prep(
    const float* __restrict__ x, const float* __restrict__ ctx,
    short* __restrict__ xb, short* __restrict__ cb,
    const float* __restrict__ Wq, const float* __restrict__ Wk,
    const float* __restrict__ Wv, const float* __restrict__ Wo,
    short* __restrict__ Wqt, short* __restrict__ Wkt,
    short* __restrict__ Wvt, short* __restrict__ Wot) {
    __shared__ short t[64][68];
    const int bx = blockIdx.x;
    if (bx < 7168) {  // elementwise fp32->bf16
        int i = bx * 256 + threadIdx.x;
        if (i < 1048576) {
            float4 v = ((const float4*)x)[i];
            s4v p = {f2bf(v.x), f2bf(v.y), f2bf(v.z), f2bf(v.w)};
            ((s4v*)xb)[i] = p;
        } else {
            int j = i - 1048576;
            float4 v = ((const float4*)ctx)[j];
            s4v p = {f2bf(v.x), f2bf(v.y), f2bf(v.z), f2bf(v.w)};
            ((s4v*)cb)[j] = p;
        }
        return;
    }
    const int idx = bx - 7168;  // 0..1023
    const int z = idx >> 8, gy = (idx >> 4) & 15, gx = idx & 15;
    const float* W;
    short* Wt;
    int K;
    switch (z) {
        case 0: W = Wq; Wt = Wqt; K = 1024; break;
        case 1: W = Wk; Wt = Wkt; K = 768; break;
        case 2: W = Wv; Wt = Wvt; K = 768; break;
        default: W = Wo; Wt = Wot; K = 1024; break;
    }
    const int k0 = gy * 64;
    if (k0 >= K) return;
    const int tid = threadIdx.x;
    const int n0 = gx * 64;
    const int kr = tid >> 4, nc = (tid & 15) * 4;
#pragma unroll
    for (int rep = 0; rep < 4; ++rep) {
        int k = kr + rep * 16;
        float4 v = *(const float4*)&W[(size_t)(k0 + k) * 1024 + n0 + nc];
        t[nc + 0][k] = f2bf(v.x);
        t[nc + 1][k] = f2bf(v.y);
        t[nc + 2][k] = f2bf(v.z);
        t[nc + 3][k] = f2bf(v.w);
    }
    __syncthreads();
    const int nr = tid >> 4, kc = (tid & 15) * 4;
#pragma unroll
    for (int rep = 0; rep < 4; ++rep) {
        int n = nr + rep * 16;
        s4v p = {t[n][kc], t[n][kc + 1], t[n][kc + 2], t[n][kc + 3]};
        *(s4v*)&Wt[(size_t)(n0 + n) * K + k0 + kc] = p;
    }
}

// ---------- fused Q/K/V projection GEMM, 512 thr / 8 waves ----------------
// R19: 3-deep counted-vmcnt pipeline. XCD-swizzled 1D grid (768):
// z = bid>>8; local = bid&255; m = local&31, n = local>>5.
__global__ __launch_bounds__(512, 6) void gemm_qkv(
    const short* __restrict__ xb, const short* __restrict__ cb,
    const short* __restrict__ Wqt, const short* __restrict__ Wkt,
    const short* __restrict__ Wvt, const float* __restrict__ bq,
    const float* __restrict__ bk, const float* __restrict__ bv,
    short* __restrict__ Qf, short* __restrict__ Kf, short* __restrict__ Vt,
    float qscale) {
    const int bid = blockIdx.x;
    const int z = bid >> 8;
    const int local = bid & 255;
    const short* A  = (z == 0) ? xb : cb;
    const short* Bt = (z == 0) ? Wqt : ((z == 1) ? Wkt : Wvt);
    const float* bias = (z == 0) ? bq : ((z == 1) ? bk : bv);
    const int K = (z == 0) ? 1024 : 768;
    const int NIT = K / 32;
    const float scale = (z == 0) ? qscale : 1.f;
    short* out = (z == 0) ? Qf : ((z == 1) ? Kf : Vt);

    __shared__ short As[12288];  // 3 x 4096 (triple buffer)
    __shared__ short Bs[12288];
    const int t = threadIdx.x, lane = t & 63, w = t >> 6;  // w 0..7
    const int lm = lane & 31, h2 = lane >> 5;
    const int wm = w & 1, wn = w >> 1;  // wn 0..3
    const int m0 = (local & 31) * 128, n0 = (local >> 5) * 128;

    const int st = t ^ ((t >> 3) & 7);
    const int srow = st >> 2, scol = (st & 3) * 8;
    const short* ga = A + (size_t)(m0 + srow) * K + scol;
    const short* gb = Bt + (size_t)(n0 + srow) * K + scol;

    const int xorv = (lm >> 1) & 7;
    const int rA0 = wm * 64 + lm, rB0 = wn * 32 + lm;

    accf acc[2] = {zero16(), zero16()};

    dma16(ga, &As[w * 512]);
    dma16(gb, &Bs[w * 512]);
    __builtin_amdgcn_sched_barrier(0);
    dma16(ga + 32, &As[4096 + w * 512]);
    dma16(gb + 32, &Bs[4096 + w * 512]);
    __builtin_amdgcn_sched_barrier(0);

    int buf = 0;
#pragma unroll 1
    for (int it = 0; it < NIT; ++it) {
        __builtin_amdgcn_sched_barrier(0);
        asm volatile("s_waitcnt vmcnt(2)" ::: "memory");
        __builtin_amdgcn_s_barrier();
        __builtin_amdgcn_sched_barrier(0);
        {
            const int nx = (it + 2 >= NIT) ? (it + 2 - NIT) : (it + 2);
            const int nb = (buf + 2 >= 3) ? (buf - 1) : (buf + 2);
            dma16(ga + nx * 32, &As[nb * 4096 + w * 512]);
            dma16(gb + nx * 32, &Bs[nb * 4096 + w * 512]);
        }
        const short* bA = &As[buf * 4096];
        const short* bB = &Bs[buf * 4096];
#pragma unroll
        for (int kk8 = 0; kk8 < 4; kk8 += 2) {
            bfr a0 = *(const bfr*)&bA[((rA0 * 4 + h2 + kk8) ^ xorv) * 8];
            bfr a1 = *(const bfr*)&bA[(((rA0 + 32) * 4 + h2 + kk8) ^ xorv) * 8];
            bfr b0 = *(const bfr*)&bB[((rB0 * 4 + h2 + kk8) ^ xorv) * 8];
            acc[0] = MFMA32(a0, b0, acc[0]);
            acc[1] = MFMA32(a1, b0, acc[1]);
        }
        buf = (buf + 1 == 3) ? 0 : buf + 1;
    }
    asm volatile("s_waitcnt vmcnt(0)" ::: "memory");
    __builtin_amdgcn_sched_barrier(0);

    const int n = n0 + wn * 32 + lm;
    const float bn = bias[n];
    const int hh = n >> 6, dd = n & 63;
#pragma unroll
    for (int mt = 0; mt < 2; ++mt) {
        const int mbase = m0 + wm * 64 + mt * 32 + 4 * h2;
        if (z != 2) {
            const int cb2 = (dd >> 4) * 512 + ((dd >> 3) & 1) * 256 + (dd & 7);
#pragma unroll
            for (int r = 0; r < 16; ++r) {
                const int m = mbase + (r & 3) + 8 * (r >> 2);
                const int bb = m >> 11, q = m & 2047;
                float v = (acc[mt][r] + bn) * scale;
                out[((size_t)((bb * 16 + hh) * 64 + (q >> 5))) * 2048 +
                    cb2 + (q & 31) * 8] = f2bf(v);
            }
        } else {
            const int dblk = dd >> 5, lmv = dd & 31;
#pragma unroll
            for (int g = 0; g < 4; ++g) {
                const int m = mbase + 8 * g;
                const int bb = m >> 11, s = m & 2047;
                const int kvt = s >> 6, kc = (s >> 4) & 3;
                const int h2v = (s >> 3) & 1, j0 = s & 7;
                s4v pq = {f2bf(acc[mt][4 * g + 0] + bn),
                          f2bf(acc[mt][4 * g + 1] + bn),
                          f2bf(acc[mt][4 * g + 2] + bn),
                          f2bf(acc[mt][4 * g + 3] + bn)};
                *(s4v*)(out +
                        ((size_t)(((bb * 16 + hh) * 32 + kvt) * 2 + dblk)) * 2048 +
                        kc * 512 + h2v * 256 + lmv * 8 + j0) = pq;
            }
        }
    }
}

// ---------- output GEMM: 128x64 tiles, 3-deep counted-vmcnt (R22) ---------
// Grid 512 (2 blocks/CU): m = bid&31 (XCD swizzle), n = bid>>5 (0..15).
// 8 waves: wm = w&3 (32-row strip), wn = w>>2 (32-col strip), acc[1]/wave.
__global__ __launch_bounds__(512, 6) void gemm_o(
    const short* __restrict__ Af, const short* __restrict__ Bt,
    const float* __restrict__ bias, float* __restrict__ out) {
    constexpr int K = 1024, NIT = 32;
    __shared__ short As[12288];  // 3 x 4096
    __shared__ short Bs[6144];   // 3 x 2048
    const int t = threadIdx.x, lane = t & 63, w = t >> 6;  // w 0..7
    const int lm = lane & 31, h2 = lane >> 5;
    const int wm = w & 3, wn = w >> 2;  // wm 0..3, wn 0..1
    const int bid = blockIdx.x;
    const int m0 = (bid & 31) * 128, n0 = (bid >> 5) * 64;

    const int st = t ^ ((t >> 3) & 7);
    const int srow = st >> 2, scol = (st & 3) * 8;
    const short* ga = Af + (size_t)(m0 + srow) * K + scol;
    const short* gb = Bt + (size_t)(n0 + srow) * K + scol;  // used t<256
    const bool bw = (w < 4);  // wave-uniform: B-staging waves

    const int xorv = (lm >> 1) & 7;
    const int rA0 = wm * 32 + lm, rB0 = wn * 32 + lm;

    accf acc = zero16();

    // prologue: batches 0,1
    dma16(ga, &As[w * 512]);
    if (bw) dma16(gb, &Bs[w * 512]);
    __builtin_amdgcn_sched_barrier(0);
    dma16(ga + 32, &As[4096 + w * 512]);
    if (bw) dma16(gb + 32, &Bs[2048 + w * 512]);
    __builtin_amdgcn_sched_barrier(0);

    int buf = 0;
#pragma unroll 1
    for (int it = 0; it < NIT; ++it) {
        __builtin_amdgcn_sched_barrier(0);
        if (bw) {
            asm volatile("s_waitcnt vmcnt(2)" ::: "memory");
        } else {
            asm volatile("s_waitcnt vmcnt(1)" ::: "memory");
        }
        __builtin_amdgcn_s_barrier();
        __builtin_amdgcn_sched_barrier(0);
        {
            const int nx = (it + 2 >= NIT) ? (it + 2 - NIT) : (it + 2);
            const int nb = (buf + 2 >= 3) ? (buf - 1) : (buf + 2);
            dma16(ga + nx * 32, &As[nb * 4096 + w * 512]);
            if (bw) dma16(gb + nx * 32, &Bs[nb * 2048 + w * 512]);
        }
        const short* bA = &As[buf * 4096];
        const short* bB = &Bs[buf * 2048];
#pragma unroll
        for (int kk8 = 0; kk8 < 4; kk8 += 2) {
            bfr a0 = *(const bfr*)&bA[((rA0 * 4 + h2 + kk8) ^ xorv) * 8];
            bfr b0 = *(const bfr*)&bB[((rB0 * 4 + h2 + kk8) ^ xorv) * 8];
            acc = MFMA32(a0, b0, acc);
        }
        buf = (buf + 1 == 3) ? 0 : buf + 1;
    }
    asm volatile("s_waitcnt vmcnt(0)" ::: "memory");
    __builtin_amdgcn_sched_barrier(0);

    const int n = n0 + wn * 32 + lm;
    const float bn = bias[n];
    const int mbase = m0 + wm * 32 + 4 * h2;
#pragma unroll
    for (int r = 0; r < 16; ++r) {
        const int m = mbase + (r & 3) + 8 * (r >> 2);
        out[(size_t)m * 1024 + n] = acc[r] + bn;
    }
}

// ---------- flash attention: full-KV blocks, in-register normalize (R22) --
// Grid 512: hidx = bid&31, qb = bid>>5 (0..15). 32 iters x 64 KV rows.
__global__ __launch_bounds__(256, 3) void attn(
    const short* __restrict__ Qf, const short* __restrict__ Kf,
    const short* __restrict__ Vt, short* __restrict__ part) {
    __shared__ short smem[16384];  // 2 bufs x (K 4KB + V 4KB) = 32 KB
    const int bid = blockIdx.x;
    const int hidx = bid & 31, qb = bid >> 5;
    const int b = hidx >> 4, h = hidx & 15;
    const int lane = threadIdx.x & 63, wv = threadIdx.x >> 6;
    const int lm = lane & 31, h2 = lane >> 5;
    const bool hb = h2 != 0;
    const int q0 = qb * 128 + wv * 32;

    const short* qbase =
        Qf + ((size_t)(hidx * 64 + (q0 >> 5))) * 2048 + lane * 8;
    bfr qf[4];
#pragma unroll
    for (int kc = 0; kc < 4; ++kc) qf[kc] = *(const bfr*)(qbase + kc * 512);

    const short* khead = Kf + (size_t)hidx * 131072;
    const short* vhead = Vt + (size_t)hidx * 131072;
    const short* gsrc =
        ((wv < 2) ? (khead + wv * 2048) : (vhead + (wv - 2) * 2048)) + lane * 8;

#pragma unroll
    for (int i = 0; i < 4; ++i)
        dma16(gsrc + i * 512, &smem[wv * 2048 + i * 512]);

    accf oa0 = zero16(), oa1 = zero16();
    float la0 = 0.f, la1 = 0.f;

#pragma unroll 1
    for (int it = 0; it < 32; ++it) {
        const int p = it & 1;
        __syncthreads();  // buf p DMA drained (vmcnt(0) before s_barrier)
        if (it + 1 < 32) {
            const short* gn = gsrc + (size_t)(it + 1) * 4096;
            short* ln = &smem[(1 - p) * 8192 + wv * 2048];
#pragma unroll
            for (int i = 0; i < 4; ++i) dma16(gn + i * 512, ln + i * 512);
        }
        const short* kb = &smem[p * 8192];
        bfr kf0[4], kf1[4], vf0[4], vf1[4];
#pragma unroll
        for (int kc = 0; kc < 4; ++kc) {
            kf0[kc] = *(const bfr*)&kb[kc * 512 + lane * 8];
            kf1[kc] = *(const bfr*)&kb[2048 + kc * 512 + lane * 8];
            vf0[kc] = *(const bfr*)&kb[4096 + kc * 512 + lane * 8];
            vf1[kc] = *(const bfr*)&kb[6144 + kc * 512 + lane * 8];
        }
        accf s0 = zero16(), s1 = zero16();
#pragma unroll
        for (int kc = 0; kc < 4; ++kc) {
            s0 = MFMA32(kf0[kc], qf[kc], s0);
            s1 = MFMA32(kf1[kc], qf[kc], s1);
        }

#pragma unroll
        for (int i = 0; i < 16; ++i) s0[i] = fexp2(s0[i]);
#pragma unroll
        for (int i = 0; i < 16; ++i) s1[i] = fexp2(s1[i]);
#pragma unroll
        for (int i = 0; i < 16; ++i) {
            if (i & 1) la1 += s0[i] + s1[i];
            else       la0 += s0[i] + s1[i];
        }

        // packed half-swap transpose
        bfr pb[4];
#pragma unroll
        for (int kc = 0; kc < 4; ++kc) {
            const accf& s = (kc < 2) ? s0 : s1;
            const int base = 8 * (kc & 1);
            unsigned Lw0 = __builtin_amdgcn_perm(__float_as_uint(s[base + 1]),
                                                 __float_as_uint(s[base + 0]),
                                                 0x07060302u);
            unsigned Lw1 = __builtin_amdgcn_perm(__float_as_uint(s[base + 3]),
                                                 __float_as_uint(s[base + 2]),
                                                 0x07060302u);
            unsigned Hw0 = __builtin_amdgcn_perm(__float_as_uint(s[base + 5]),
                                                 __float_as_uint(s[base + 4]),
                                                 0x07060302u);
            unsigned Hw1 = __builtin_amdgcn_perm(__float_as_uint(s[base + 7]),
                                                 __float_as_uint(s[base + 6]),
                                                 0x07060302u);
            unsigned c0 = hb ? Lw0 : Hw0;
            unsigned c1 = hb ? Lw1 : Hw1;
            unsigned r0 = (unsigned)__shfl_xor((int)c0, 32);
            unsigned r1 = (unsigned)__shfl_xor((int)c1, 32);
            u4v pw = {hb ? r0 : Lw0, hb ? r1 : Lw1,
                      hb ? Hw0 : r0, hb ? Hw1 : r1};
            pb[kc] = __builtin_bit_cast(bfr, pw);
        }

#pragma unroll
        for (int kc = 0; kc < 4; ++kc) {
            oa0 = MFMA32(vf0[kc], pb[kc], oa0);
            oa1 = MFMA32(vf1[kc], pb[kc], oa1);
        }
    }

    float ls = la0 + la1;
    ls += __shfl_xor(ls, 32);
    const float iv = 1.f / ls;

    short* orow = part + (size_t)(b * 2048 + q0 + lm) * 1024 + h * 64;
#pragma unroll
    for (int dt = 0; dt < 2; ++dt) {
        const accf& oa = dt ? oa1 : oa0;
#pragma unroll
        for (int g = 0; g < 4; ++g) {
            const int d0 = dt * 32 + 4 * h2 + 8 * g;
            s4v p = {f2bf(oa[4 * g + 0] * iv), f2bf(oa[4 * g + 1] * iv),
                     f2bf(oa[4 * g + 2] * iv), f2bf(oa[4 * g + 3] * iv)};
            *(s4v*)(orow + d0) = p;
        }
    }
}

}  // namespace

extern "C" void kernel_launch(void* const* d_in, const int* in_sizes, int n_in,
                              void* d_out, int out_size, void* d_ws,
                              size_t ws_size, hipStream_t stream) {
    const float* x   = (const float*)d_in[0];
    const float* ctx = (const float*)d_in[1];
    const float* Wq  = (const float*)d_in[2];
    const float* bq  = (const float*)d_in[3];
    const float* Wk  = (const float*)d_in[4];
    const float* bk  = (const float*)d_in[5];
    const float* Wv  = (const float*)d_in[6];
    const float* bv  = (const float*)d_in[7];
    const float* Wo  = (const float*)d_in[8];
    const float* bo  = (const float*)d_in[9];

    short* xb  = (short*)d_ws;
    short* cb  = xb + (size_t)4096 * 1024;
    short* Wqt = cb + (size_t)4096 * 768;
    short* Wkt = Wqt + (size_t)1024 * 1024;
    short* Wvt = Wkt + (size_t)1024 * 768;
    short* Wot = Wvt + (size_t)1024 * 768;
    short* Qf  = Wot + (size_t)1024 * 1024;  // frag-order, pre-scaled
    short* Kf  = Qf + (size_t)4096 * 1024;   // frag-order
    short* Vt  = Kf + (size_t)4096 * 1024;   // frag-order V^T
    short* p0  = Vt + (size_t)4096 * 1024;   // final normalized attn out

    prep<<<8192, 256, 0, stream>>>(x, ctx, xb, cb, Wq, Wk, Wv, Wo,
                                   Wqt, Wkt, Wvt, Wot);

    const float qscale = 0.125f * 1.44269504088896f;
    gemm_qkv<<<768, 512, 0, stream>>>(xb, cb, Wqt, Wkt, Wvt,
                                      bq, bk, bv, Qf, Kf, Vt, qscale);

    attn<<<512, 256, 0, stream>>>(Qf, Kf, Vt, p0);

    gemm_o<<<512, 512, 0, stream>>>(p0, Wot, bo, (float*)d_out);
}